// Round 5
// baseline (342.267 us; speedup 1.0000x reference)
//
#include <hip/hip_runtime.h>
#include <cstdint>
#include <cstddef>

#define ROWS   4096
#define COLS   50000    // logits used (last column of 50001 dropped)
#define STRIDE 50001
#define NTHR   256

typedef float f4 __attribute__((ext_vector_type(4)));

// -log(ONEHOT_MIN) = -log(1e-4)
__device__ const float NEG_LOG_LOW = 9.210340371976184f;
// fixed-point scale for the deterministic integer mean accumulator
#define FIXED_SCALE 4294967296.0   // 2^32

// One block per row: s = sum_j exp(x_j); row_loss = (log s - x_t) + 9.21034*(1 - exp(x_t)/s).
// sum_p == 1 up to the 1e-7 clip (contribution ~1e-8 vs 0.41 threshold).
// No max-subtraction: N(0,1) logits => sum exp ~ 8e4, no fp32 overflow risk.
// Final mean fused: u64 fixed-point atomicAdd (exact, order-independent =>
// deterministic), last block (device-scope counter) writes out[0].
// d_ws[0..7]=u64 sum, d_ws[8..11]=u32 counter — zeroed by a memset node each call.
__global__ __launch_bounds__(NTHR) void sce_row_kernel(
        const float* __restrict__ pred,
        const int* __restrict__ labels,     // int32 (JAX x64 disabled)
        float* __restrict__ out,
        unsigned long long* __restrict__ ws)
{
    const int row = blockIdx.x;
    const int tid = threadIdx.x;
    const float* rowp = pred + (size_t)row * STRIDE;

    __shared__ float s_xtrue;
    __shared__ float s_part[NTHR / 64];
    if (tid == 0) {
        int l = labels[row];               // 0..49999, in row bounds
        s_xtrue = rowp[l];
    }

    // Row base alignment varies: (row*50001*4) % 16 == (row%4)*4.
    // Peel 'lead' scalars so the bulk is 16B-aligned float4.
    const uintptr_t a = (uintptr_t)rowp;
    const int mis  = (int)((a & 15) >> 2);   // 0..3 misaligned floats
    const int lead = (4 - mis) & 3;
    const int nrem = COLS - lead;
    const int nvec = nrem >> 2;              // max elem idx: lead + 4*nvec - 1 <= 49999
    const int tail = nrem & 3;
    const f4* __restrict__ v4 = (const f4*)(rowp + lead);

    // 4x-unrolled non-temporal streaming: 4 loads in flight, 4 accumulators.
    float sum0 = 0.0f, sum1 = 0.0f, sum2 = 0.0f, sum3 = 0.0f;
    int i = tid;
    for (; i + 3 * NTHR < nvec; i += 4 * NTHR) {
        f4 va = __builtin_nontemporal_load(v4 + i);
        f4 vb = __builtin_nontemporal_load(v4 + i + NTHR);
        f4 vc = __builtin_nontemporal_load(v4 + i + 2 * NTHR);
        f4 vd = __builtin_nontemporal_load(v4 + i + 3 * NTHR);
        sum0 += __expf(va.x) + __expf(va.y) + __expf(va.z) + __expf(va.w);
        sum1 += __expf(vb.x) + __expf(vb.y) + __expf(vb.z) + __expf(vb.w);
        sum2 += __expf(vc.x) + __expf(vc.y) + __expf(vc.z) + __expf(vc.w);
        sum3 += __expf(vd.x) + __expf(vd.y) + __expf(vd.z) + __expf(vd.w);
    }
    for (; i < nvec; i += NTHR) {
        f4 va = __builtin_nontemporal_load(v4 + i);
        sum0 += __expf(va.x) + __expf(va.y) + __expf(va.z) + __expf(va.w);
    }
    float sum = (sum0 + sum1) + (sum2 + sum3);

    // lead scalars (<=3) on wave 0, tail scalars (<=3) on wave 1
    if (tid < lead)
        sum += __expf(rowp[tid]);
    if (tid >= 64 && tid < 64 + tail)
        sum += __expf(rowp[lead + 4 * nvec + (tid - 64)]);

    // wave(64) shuffle reduce
    #pragma unroll
    for (int off = 32; off > 0; off >>= 1)
        sum += __shfl_down(sum, off, 64);
    if ((tid & 63) == 0) s_part[tid >> 6] = sum;
    __syncthreads();

    if (tid == 0) {
        float s = s_part[0] + s_part[1] + s_part[2] + s_part[3];
        float logZ   = logf(s);
        float xt     = s_xtrue;
        float p_true = __expf(xt) / s;            // exp(x_true - logZ)
        float row_loss = (logZ - xt) + NEG_LOG_LOW * (1.0f - p_true);

        // row_loss > 0 always (ce ~ [5.8,16.8], rce >= 0); quantize to 2^-32.
        unsigned long long fx =
            (unsigned long long)((double)row_loss * FIXED_SCALE);
        atomicAdd(ws, fx);                        // device-scope, exact int add
        __threadfence();                          // sum-add visible before count
        unsigned int old = atomicAdd((unsigned int*)(ws + 1), 1u);
        if (old == ROWS - 1) {                    // last block finalizes
            unsigned long long total = atomicAdd(ws, 0ULL);  // coherent read
            out[0] = (float)((double)total * (1.0 / FIXED_SCALE / (double)ROWS));
        }
    }
}

extern "C" void kernel_launch(void* const* d_in, const int* in_sizes, int n_in,
                              void* d_out, int out_size, void* d_ws, size_t ws_size,
                              hipStream_t stream)
{
    const float* pred   = (const float*)d_in[0];
    const int*   labels = (const int*)d_in[1];   // int32 on device
    float*       out    = (float*)d_out;
    unsigned long long* ws = (unsigned long long*)d_ws;

    // zero the 16-byte accumulator block (graph-legal memset node);
    // required every call: harness doesn't re-poison/restore d_ws between replays.
    hipMemsetAsync(d_ws, 0, 16, stream);
    sce_row_kernel<<<ROWS, NTHR, 0, stream>>>(pred, labels, out, ws);
}

// Round 6
// 135.043 us; speedup vs baseline: 2.5345x; 2.5345x over previous
//
#include <hip/hip_runtime.h>
#include <cstdint>
#include <cstddef>

#define ROWS   4096
#define COLS   50000    // logits used (last column of 50001 dropped)
#define STRIDE 50001
#define NTHR   256

typedef float f4 __attribute__((ext_vector_type(4)));

// -log(ONEHOT_MIN) = -log(1e-4)
__device__ const float NEG_LOG_LOW = 9.210340371976184f;

// One block per row: s = sum_j exp(x_j); row_loss = (log s - x_t) + 9.21034*(1 - exp(x_t)/s).
// sum_p == 1 up to the 1e-7 clip (contribution ~1e-8 vs 0.41 threshold).
// No max-subtraction: N(0,1) logits => sum exp ~ 8e4, no fp32 overflow risk.
// NOTE: no hipMemsetAsync in the timed path — a graph memset node costs
// ~200-500us on this stack (R5 regression, confirmed in rocprof).
__global__ __launch_bounds__(NTHR) void sce_row_kernel(
        const float* __restrict__ pred,
        const int* __restrict__ labels,     // int32 (JAX x64 disabled)
        float* __restrict__ row_loss)
{
    const int row = blockIdx.x;
    const int tid = threadIdx.x;
    const float* rowp = pred + (size_t)row * STRIDE;

    __shared__ float s_xtrue;
    __shared__ float s_part[NTHR / 64];
    if (tid == 0) {
        int l = labels[row];               // 0..49999, in row bounds
        s_xtrue = rowp[l];
    }

    // Row base alignment varies: (row*50001*4) % 16 == (row%4)*4.
    // Peel 'lead' scalars so the bulk is 16B-aligned float4.
    const uintptr_t a = (uintptr_t)rowp;
    const int mis  = (int)((a & 15) >> 2);   // 0..3 misaligned floats
    const int lead = (4 - mis) & 3;
    const int nrem = COLS - lead;
    const int nvec = nrem >> 2;              // max elem idx: lead + 4*nvec - 1 <= 49999
    const int tail = nrem & 3;
    const f4* __restrict__ v4 = (const f4*)(rowp + lead);

    // 4x-unrolled non-temporal streaming: 4 loads in flight, 4 accumulators.
    float sum0 = 0.0f, sum1 = 0.0f, sum2 = 0.0f, sum3 = 0.0f;
    int i = tid;
    for (; i + 3 * NTHR < nvec; i += 4 * NTHR) {
        f4 va = __builtin_nontemporal_load(v4 + i);
        f4 vb = __builtin_nontemporal_load(v4 + i + NTHR);
        f4 vc = __builtin_nontemporal_load(v4 + i + 2 * NTHR);
        f4 vd = __builtin_nontemporal_load(v4 + i + 3 * NTHR);
        sum0 += __expf(va.x) + __expf(va.y) + __expf(va.z) + __expf(va.w);
        sum1 += __expf(vb.x) + __expf(vb.y) + __expf(vb.z) + __expf(vb.w);
        sum2 += __expf(vc.x) + __expf(vc.y) + __expf(vc.z) + __expf(vc.w);
        sum3 += __expf(vd.x) + __expf(vd.y) + __expf(vd.z) + __expf(vd.w);
    }
    for (; i < nvec; i += NTHR) {
        f4 va = __builtin_nontemporal_load(v4 + i);
        sum0 += __expf(va.x) + __expf(va.y) + __expf(va.z) + __expf(va.w);
    }
    float sum = (sum0 + sum1) + (sum2 + sum3);

    // lead scalars (<=3) on wave 0, tail scalars (<=3) on wave 1
    if (tid < lead)
        sum += __expf(rowp[tid]);
    if (tid >= 64 && tid < 64 + tail)
        sum += __expf(rowp[lead + 4 * nvec + (tid - 64)]);

    // wave(64) shuffle reduce
    #pragma unroll
    for (int off = 32; off > 0; off >>= 1)
        sum += __shfl_down(sum, off, 64);
    if ((tid & 63) == 0) s_part[tid >> 6] = sum;
    __syncthreads();

    if (tid == 0) {
        float s = s_part[0] + s_part[1] + s_part[2] + s_part[3];
        float logZ   = logf(s);
        float xt     = s_xtrue;
        float p_true = __expf(xt) / s;            // exp(x_true - logZ)
        row_loss[row] = (logZ - xt) + NEG_LOG_LOW * (1.0f - p_true);
    }
}

// Single-block deterministic reduction of the 4096 row losses -> mean.
__global__ __launch_bounds__(NTHR) void sce_reduce_kernel(
        const float* __restrict__ row_loss,
        float* __restrict__ out)
{
    const int tid = threadIdx.x;
    double sum = 0.0;
    for (int i = tid; i < ROWS; i += NTHR)
        sum += (double)row_loss[i];
    #pragma unroll
    for (int off = 32; off > 0; off >>= 1)
        sum += __shfl_down(sum, off, 64);
    __shared__ double s_part[NTHR / 64];
    if ((tid & 63) == 0) s_part[tid >> 6] = sum;
    __syncthreads();
    if (tid == 0)
        out[0] = (float)((s_part[0] + s_part[1] + s_part[2] + s_part[3]) *
                         (1.0 / (double)ROWS));
}

extern "C" void kernel_launch(void* const* d_in, const int* in_sizes, int n_in,
                              void* d_out, int out_size, void* d_ws, size_t ws_size,
                              hipStream_t stream)
{
    const float* pred   = (const float*)d_in[0];
    const int*   labels = (const int*)d_in[1];   // int32 on device
    float*       out    = (float*)d_out;
    float*       rl     = (float*)d_ws;          // 4096 floats = 16 KiB scratch

    sce_row_kernel<<<ROWS, NTHR, 0, stream>>>(pred, labels, rl);
    sce_reduce_kernel<<<1, NTHR, 0, stream>>>(rl, out);
}